// Round 8
// baseline (8578.759 us; speedup 1.0000x reference)
//
#include <hip/hip_runtime.h>

#define TPB 256

static inline int cdiv(int a, int b) { return (a + b - 1) / b; }

// ---------------------------------------------------------------------------
// Scale-0 cost volume: cost[b,h,w,d] = sum_c |fl[b,h,w,c] - fr[b,h,w-d,c]|,
// fr treated as 0 where w < d. Output layout (B,H,W,D), d fastest.
// ---------------------------------------------------------------------------
template <int C>
__global__ void cost0_kernel(const float* __restrict__ fl, const float* __restrict__ fr,
                             float* __restrict__ out, int B, int H, int W, int D) {
    int idx = blockIdx.x * blockDim.x + threadIdx.x;
    int total = B * H * W * D;
    if (idx >= total) return;
    int d = idx % D; int t = idx / D;
    int w = t % W;   t /= W;
    int h = t % H;   int b = t / H;
    const float* pl = fl + (size_t)((b * H + h) * W + w) * C;
    float s = 0.f;
    if (w >= d) {
        const float* pr = fr + (size_t)((b * H + h) * W + (w - d)) * C;
#pragma unroll
        for (int c = 0; c < C; ++c) s += fabsf(pl[c] - pr[c]);
    } else {
#pragma unroll
        for (int c = 0; c < C; ++c) s += fabsf(pl[c]);
    }
    out[idx] = s;
}

// ---------------------------------------------------------------------------
// _build_volume_2d3 with faithful TF tile+reshape scrambling.
// ---------------------------------------------------------------------------
template <int C, int K, int W>
__global__ void cost2d3_kernel(const float* __restrict__ fl, const float* __restrict__ fr,
                               const float* __restrict__ wflow, float* __restrict__ out,
                               int B, int H, int md) {
    int idx = blockIdx.x * blockDim.x + threadIdx.x;
    int total = B * K * H * W;
    if (idx >= total) return;
    int x = idx % W; int t0 = idx / W;
    int y = t0 % H;  int n = t0 / H;
    int a = n / K, t = n % K;

    // flow value (scrambled indexing into wflow)
    int rem2 = (t * H + y) * W + x;
    int hd = rem2 / (W * K);
    int wd = (rem2 / K) % W;
    float bd = wflow[(a * H + hd) * W + wd] - (float)(t - md + 1);

    float xq = (float)x - bd;
    xq = fminf(fmaxf(xq, 0.f), (float)(W - 1));
    int x0 = (int)floorf(xq);
    if (x0 > W - 2) x0 = W - 2;
    float al = xq - (float)x0;

    int base  = ((t * H + y) * W + x)  * C;
    int base0 = ((t * H + y) * W + x0) * C;
    int base1 = base0 + C;

    float s = 0.f;
#pragma unroll
    for (int c = 0; c < C; ++c) {
        int r = base + c;
        int h1 = r / (W * C * K); int w1 = (r / (C * K)) % W; int c1 = (r / K) % C;
        float av = fl[((a * H + h1) * W + w1) * C + c1];

        int r0 = base0 + c;
        int h0 = r0 / (W * C * K); int w0 = (r0 / (C * K)) % W; int c0 = (r0 / K) % C;
        float f0 = fr[((a * H + h0) * W + w0) * C + c0];

        int r1 = base1 + c;
        int h1b = r1 / (W * C * K); int w1b = (r1 / (C * K)) % W; int c1b = (r1 / K) % C;
        float f1 = fr[((a * H + h1b) * W + w1b) * C + c1b];

        float wv = f0 * (1.f - al) + f1 * al;
        s += fabsf(av - wv);
    }
    out[idx] = s;
}

// ---------------------------------------------------------------------------
// 3x3x3 SAME conv, channels-last, strip along d3, q-slice PER BLOCK.
//
// r6/r7 post-mortem: the r6 body (scalar loads, unroll-2 ci) is the best-
// measured inner loop (174us vs 218us for float2/unroll-1) but occupancy was
// GRID-capped at 4 blocks/CU (1024 blocks, 27.6KB LDS). Here:
//  - q (co-block id) comes from blockIdx (q = bid % NQ): grid x NQ, and each
//    block stages only its 27*CIN*CO_BLK weight slice (s0: 3456B) -> LDS and
//    grid both stop capping residency; weight ds_reads become same-address
//    broadcasts (free).
//  - TD=6 at s0 (12 at r6) doubles the thread count again -> 2048 blocks =
//    8 blocks/CU = up to 32 waves/CU, vs ~12 before, for a latency-bound body.
//  - adjacent blocks (bid/NQ equal) cover the same pixels -> input L2 reuse.
//  - inner body IDENTICAL to r6 (scalar seg, unroll2 ci, unroll1 kd/kh):
//    the only config measured spill-free at 64 VGPR.
//  - launch_bounds(256,8) caps VGPR at 64 = 8 waves/SIMD.
// ---------------------------------------------------------------------------
template <int CIN, int COUT, int CO_BLK, int TD, bool RELU>
__global__ void __launch_bounds__(TPB, 8)
conv3d_stripq(const float* __restrict__ in, const float* __restrict__ w,
              float* __restrict__ out, int B, int D1, int D2, int D3) {
    constexpr int NQ  = COUT / CO_BLK;
    constexpr int WSZ = 27 * CIN * CO_BLK;
    __shared__ __align__(16) float ws[WSZ];

    const int nblk = D3 / TD;   // exact by construction
    int q  = blockIdx.x % NQ;
    int pb = blockIdx.x / NQ;

    for (int i = threadIdx.x; i < WSZ; i += TPB) {
        int g = i / CO_BLK, cb = i % CO_BLK;
        ws[i] = w[g * COUT + q * CO_BLK + cb];
    }
    __syncthreads();

    int idx = pb * TPB + threadIdx.x;
    int total = B * D1 * D2 * nblk;
    if (idx >= total) return;          // grids are exact; kept for safety
    int t3 = (idx % nblk) * TD; int t = idx / nblk;
    int d2 = t % D2; t /= D2;
    int d1 = t % D1; int b = t / D1;

    float acc[TD][CO_BLK];
#pragma unroll
    for (int o = 0; o < TD; ++o)
#pragma unroll
        for (int cb = 0; cb < CO_BLK; ++cb) acc[o][cb] = 0.f;

#pragma unroll 1
    for (int kd = 0; kd < 3; ++kd) {
        int z = d1 + kd - 1; if (z < 0 || z >= D1) continue;
#pragma unroll 1
        for (int kh = 0; kh < 3; ++kh) {
            int y = d2 + kh - 1; if (y < 0 || y >= D2) continue;
            const float* rowp = in + (size_t)((b * D1 + z) * D2 + y) * D3 * CIN;
            const float* wb = ws + (kd * 3 + kh) * 3 * CIN * CO_BLK;

#pragma unroll 2
            for (int ci = 0; ci < CIN; ++ci) {
                float seg[TD + 2];
#pragma unroll
                for (int p = 0; p < TD + 2; ++p) {
                    int x = t3 + p - 1;
                    seg[p] = (x >= 0 && x < D3) ? rowp[x * CIN + ci] : 0.f;
                }
#pragma unroll
                for (int kw = 0; kw < 3; ++kw) {
                    float wq[CO_BLK];
                    if constexpr (CO_BLK == 4) {
                        float4 wv = *(const float4*)(wb + (kw * CIN + ci) * 4);
                        wq[0] = wv.x; wq[1] = wv.y; wq[2] = wv.z; wq[3] = wv.w;
                    } else if constexpr (CO_BLK == 2) {
                        float2 wv = *(const float2*)(wb + (kw * CIN + ci) * 2);
                        wq[0] = wv.x; wq[1] = wv.y;
                    } else {
                        wq[0] = wb[kw * CIN + ci];
                    }
#pragma unroll
                    for (int o = 0; o < TD; ++o) {
                        float v = seg[o + kw];
#pragma unroll
                        for (int cb = 0; cb < CO_BLK; ++cb) acc[o][cb] += v * wq[cb];
                    }
                }
            }
        }
    }

    float* op = out + ((size_t)((b * D1 + d1) * D2 + d2) * D3 + t3) * COUT + q * CO_BLK;
#pragma unroll
    for (int o = 0; o < TD; ++o) {
        if constexpr (CO_BLK == 4) {
            float4 v;
            v.x = RELU ? fmaxf(acc[o][0], 0.f) : acc[o][0];
            v.y = RELU ? fmaxf(acc[o][1], 0.f) : acc[o][1];
            v.z = RELU ? fmaxf(acc[o][2], 0.f) : acc[o][2];
            v.w = RELU ? fmaxf(acc[o][3], 0.f) : acc[o][3];
            *(float4*)(op + o * COUT) = v;
        } else if constexpr (CO_BLK == 2) {
            float2 v;
            v.x = RELU ? fmaxf(acc[o][0], 0.f) : acc[o][0];
            v.y = RELU ? fmaxf(acc[o][1], 0.f) : acc[o][1];
            *(float2*)(op + o * COUT) = v;
        } else {
            op[o * COUT] = RELU ? fmaxf(acc[o][0], 0.f) : acc[o][0];
        }
    }
}

// ---------------------------------------------------------------------------
// COUT=1 conv (regularizer output layer). One thread PER VOXEL (d3-fastest
// -> full grid). float4 dot over ci, weights in LDS. r5-r7: not in top-5.
// ---------------------------------------------------------------------------
template <int CIN>
__global__ void __launch_bounds__(TPB)
conv3d_out1(const float* __restrict__ in, const float* __restrict__ w,
            float* __restrict__ out, int B, int D1, int D2, int D3) {
    constexpr int WSZ = 27 * CIN;
    __shared__ __align__(16) float ws[WSZ];
    for (int i = threadIdx.x; i < WSZ; i += blockDim.x) ws[i] = w[i];
    __syncthreads();

    int idx = blockIdx.x * blockDim.x + threadIdx.x;
    int total = B * D1 * D2 * D3;
    if (idx >= total) return;
    int d3 = idx % D3; int t = idx / D3;
    int d2 = t % D2;   t /= D2;
    int d1 = t % D1;   int b = t / D1;

    float acc = 0.f;
#pragma unroll 1
    for (int kd = 0; kd < 3; ++kd) {
        int z = d1 + kd - 1; if (z < 0 || z >= D1) continue;
#pragma unroll 1
        for (int kh = 0; kh < 3; ++kh) {
            int y = d2 + kh - 1; if (y < 0 || y >= D2) continue;
            const float* rowp = in + (size_t)((b * D1 + z) * D2 + y) * D3 * CIN;
            const float* wb = ws + (kd * 3 + kh) * 3 * CIN;
#pragma unroll
            for (int kw = 0; kw < 3; ++kw) {
                int x = d3 + kw - 1; if (x < 0 || x >= D3) continue;
                const float* ip = rowp + x * CIN;
                const float* wp = wb + kw * CIN;
#pragma unroll
                for (int c4 = 0; c4 < CIN / 4; ++c4) {
                    float4 iv = *(const float4*)(ip + c4 * 4);
                    float4 wv = *(const float4*)(wp + c4 * 4);
                    acc += iv.x * wv.x + iv.y * wv.y + iv.z * wv.z + iv.w * wv.w;
                }
            }
        }
    }
    out[idx] = acc;
}

// ---------------------------------------------------------------------------
// softmax(-cost) over last dim D, weighted by dvals = dstart + d
// ---------------------------------------------------------------------------
__global__ void softargmax_kernel(const float* __restrict__ in, float* __restrict__ out,
                                  int npix, int D, float dstart) {
    int idx = blockIdx.x * blockDim.x + threadIdx.x;
    if (idx >= npix) return;
    const float* p = in + (size_t)idx * D;
    float m = -1e30f;
    for (int d = 0; d < D; ++d) m = fmaxf(m, -p[d]);
    float s = 0.f, wsum = 0.f;
    for (int d = 0; d < D; ++d) {
        float e = expf(-p[d] - m);
        s += e;
        wsum += e * (dstart + (float)d);
    }
    out[idx] = wsum / s;
}

// ---------------------------------------------------------------------------
// Bilinear upsample (jax.image.resize upscale == half-pixel + clamp).
// Optional add of prev prediction.
// ---------------------------------------------------------------------------
__global__ void upsample_kernel(const float* __restrict__ disp, int inH, int inW,
                                const float* __restrict__ prev, float* __restrict__ out,
                                int B, int OH, int OW) {
    int idx = blockIdx.x * blockDim.x + threadIdx.x;
    int total = B * OH * OW;
    if (idx >= total) return;
    int x = idx % OW; int t = idx / OW;
    int y = t % OH;   int b = t / OH;
    float sy = (y + 0.5f) * ((float)inH / (float)OH) - 0.5f;
    float sx = (x + 0.5f) * ((float)inW / (float)OW) - 0.5f;
    sy = fminf(fmaxf(sy, 0.f), (float)(inH - 1));
    sx = fminf(fmaxf(sx, 0.f), (float)(inW - 1));
    int y0 = (int)sy; if (y0 > inH - 2) y0 = inH - 2;
    int x0 = (int)sx; if (x0 > inW - 2) x0 = inW - 2;
    float ay = sy - (float)y0, ax = sx - (float)x0;
    const float* p = disp + (size_t)(b * inH + y0) * inW + x0;
    float v00 = p[0], v01 = p[1], v10 = p[inW], v11 = p[inW + 1];
    float v0 = v00 * (1.f - ax) + v01 * ax;
    float v1 = v10 * (1.f - ax) + v11 * ax;
    float v  = v0 * (1.f - ay) + v1 * ay;
    if (prev) v += prev[idx];
    out[idx] = v;
}

// ---------------------------------------------------------------------------
// Antialiased bilinear downsample by integer factor F (jax resize default
// antialias=True): triangle kernel radius F, weights renormalized over valid
// taps. Result multiplied by `mult`.
// ---------------------------------------------------------------------------
__global__ void downsample_kernel(const float* __restrict__ in, int inH, int inW,
                                  float* __restrict__ out, int B, int OH, int OW,
                                  int F, float mult) {
    int idx = blockIdx.x * blockDim.x + threadIdx.x;
    int total = B * OH * OW;
    if (idx >= total) return;
    int x = idx % OW; int t = idx / OW;
    int y = t % OH;   int b = t / OH;
    float sy = (y + 0.5f) * (float)F - 0.5f;
    float sx = (x + 0.5f) * (float)F - 0.5f;
    float invF = 1.f / (float)F;
    int jlo = (int)floorf(sy) - F + 1, jhi = (int)floorf(sy) + F;
    int ilo = (int)floorf(sx) - F + 1, ihi = (int)floorf(sx) + F;

    float wxsum = 0.f;
    for (int i = ilo; i <= ihi; ++i) {
        if (i < 0 || i >= inW) continue;
        float wx = 1.f - fabsf(sx - (float)i) * invF;
        if (wx > 0.f) wxsum += wx;
    }
    float wysum = 0.f, acc = 0.f;
    for (int j = jlo; j <= jhi; ++j) {
        if (j < 0 || j >= inH) continue;
        float wy = 1.f - fabsf(sy - (float)j) * invF;
        if (wy <= 0.f) continue;
        wysum += wy;
        const float* row = in + (size_t)(b * inH + j) * inW;
        float r = 0.f;
        for (int i = ilo; i <= ihi; ++i) {
            if (i < 0 || i >= inW) continue;
            float wx = 1.f - fabsf(sx - (float)i) * invF;
            if (wx > 0.f) r += wx * row[i];
        }
        acc += wy * r;
    }
    out[idx] = mult * acc / (wysum * wxsum);
}

// ---------------------------------------------------------------------------

extern "C" void kernel_launch(void* const* d_in, const int* in_sizes, int n_in,
                              void* d_out, int out_size, void* d_ws, size_t ws_size,
                              hipStream_t stream) {
    const float* fl0 = (const float*)d_in[0];
    const float* fr0 = (const float*)d_in[1];
    const float* fl1 = (const float*)d_in[2];
    const float* fr1 = (const float*)d_in[3];
    const float* fl2 = (const float*)d_in[4];
    const float* fr2 = (const float*)d_in[5];
    const float* w0_in  = (const float*)d_in[6];
    const float* w0_mid = (const float*)d_in[7];
    const float* w0_out = (const float*)d_in[8];
    const float* w1_in  = (const float*)d_in[9];
    const float* w1_mid = (const float*)d_in[10];
    const float* w1_out = (const float*)d_in[11];
    const float* w2_in  = (const float*)d_in[12];
    const float* w2_mid = (const float*)d_in[13];
    const float* w2_out = (const float*)d_in[14];
    float* out = (float*)d_out;

    const int B = 16;
    const int OH = 512, OW = 1024;
    const int P = B * OH * OW;            // one prediction block (fp32 elements)

    const size_t BUF = 10485760;          // max conv volume: 16*128*256*5*4
    float* bufA  = (float*)d_ws;
    float* bufB  = bufA + BUF;
    float* disp  = bufB + BUF;
    float* wflow = disp + 524288;

    // ======================= scale 0 =======================
    {
        const int H = 32, W = 64, D = 12;
        int vox = B * H * W * D;              // 393216
        int npix = B * H * W;                 // 32768
        // TD=6 -> nblk=2; pixel-strip threads = npix*2 = 65536 = 256 blocks/q
        int g_mid = (npix * 2 / TPB) * 8;     // NQ=8 -> 2048 blocks
        cost0_kernel<16><<<cdiv(vox, TPB), TPB, 0, stream>>>(fl0, fr0, bufA, B, H, W, D);
        conv3d_stripq<1, 16, 2, 6, true ><<<g_mid, TPB, 0, stream>>>(bufA, w0_in,          bufB, B, H, W, D);
        conv3d_stripq<16, 16, 2, 6, true><<<g_mid, TPB, 0, stream>>>(bufB, w0_mid,         bufA, B, H, W, D);
        conv3d_stripq<16, 16, 2, 6, true><<<g_mid, TPB, 0, stream>>>(bufA, w0_mid + 6912,  bufB, B, H, W, D);
        conv3d_stripq<16, 16, 2, 6, true><<<g_mid, TPB, 0, stream>>>(bufB, w0_mid + 13824, bufA, B, H, W, D);
        conv3d_out1<16><<<cdiv(vox, TPB), TPB, 0, stream>>>(bufA, w0_out, bufB, B, H, W, D);
        softargmax_kernel<<<cdiv(npix, TPB), TPB, 0, stream>>>(bufB, disp, npix, D, 0.f);
        upsample_kernel<<<cdiv(P, TPB), TPB, 0, stream>>>(disp, H, W, nullptr, out, B, OH, OW);
    }

    // ======================= scale 1 =======================
    {
        const int H = 64, W = 128, K = 5, md = 3;
        int npix = B * H * W;                 // 131072
        downsample_kernel<<<cdiv(npix, TPB), TPB, 0, stream>>>(out, OH, OW, wflow, B, H, W, 8, 64.f / 512.f);
        int vox = B * K * H * W;              // 655360
        int g_c1 = (npix / TPB) * 4;          // CO_BLK=1, NQ=4 -> 2048 blocks
        cost2d3_kernel<16, 5, 128><<<cdiv(vox, TPB), TPB, 0, stream>>>(fl1, fr1, wflow, bufA, B, H, md);
        conv3d_stripq<1, 4, 1, 5, true ><<<g_c1, TPB, 0, stream>>>(bufA, w1_in,        bufB, B, H, W, K);
        conv3d_stripq<4, 4, 1, 5, true ><<<g_c1, TPB, 0, stream>>>(bufB, w1_mid,       bufA, B, H, W, K);
        conv3d_stripq<4, 4, 1, 5, true ><<<g_c1, TPB, 0, stream>>>(bufA, w1_mid + 432, bufB, B, H, W, K);
        conv3d_stripq<4, 4, 1, 5, true ><<<g_c1, TPB, 0, stream>>>(bufB, w1_mid + 864, bufA, B, H, W, K);
        conv3d_out1<4><<<cdiv(vox, TPB), TPB, 0, stream>>>(bufA, w1_out, bufB, B, H, W, K);
        softargmax_kernel<<<cdiv(npix, TPB), TPB, 0, stream>>>(bufB, disp, npix, K, -2.f);
        upsample_kernel<<<cdiv(P, TPB), TPB, 0, stream>>>(disp, H, W, out, out + P, B, OH, OW);
    }

    // ======================= scale 2 =======================
    {
        const int H = 128, W = 256, K = 5, md = 3;
        int npix = B * H * W;                 // 524288
        downsample_kernel<<<cdiv(npix, TPB), TPB, 0, stream>>>(out + P, OH, OW, wflow, B, H, W, 4, 128.f / 512.f);
        int vox = B * K * H * W;              // 2621440
        int g_c2 = (npix / TPB) * 2;          // CO_BLK=2, NQ=2 -> 4096 blocks
        cost2d3_kernel<16, 5, 256><<<cdiv(vox, TPB), TPB, 0, stream>>>(fl2, fr2, wflow, bufA, B, H, md);
        conv3d_stripq<1, 4, 2, 5, true ><<<g_c2, TPB, 0, stream>>>(bufA, w2_in,        bufB, B, H, W, K);
        conv3d_stripq<4, 4, 2, 5, true ><<<g_c2, TPB, 0, stream>>>(bufB, w2_mid,       bufA, B, H, W, K);
        conv3d_stripq<4, 4, 2, 5, true ><<<g_c2, TPB, 0, stream>>>(bufA, w2_mid + 432, bufB, B, H, W, K);
        conv3d_stripq<4, 4, 2, 5, true ><<<g_c2, TPB, 0, stream>>>(bufB, w2_mid + 864, bufA, B, H, W, K);
        conv3d_out1<4><<<cdiv(vox, TPB), TPB, 0, stream>>>(bufA, w2_out, bufB, B, H, W, K);
        softargmax_kernel<<<cdiv(npix, TPB), TPB, 0, stream>>>(bufB, disp, npix, K, -2.f);
        upsample_kernel<<<cdiv(P, TPB), TPB, 0, stream>>>(disp, H, W, out + P, out + 2 * P, B, OH, OW);
    }
}

// Round 9
// 1390.873 us; speedup vs baseline: 6.1679x; 6.1679x over previous
//
#include <hip/hip_runtime.h>

#define TPB 256

static inline int cdiv(int a, int b) { return (a + b - 1) / b; }

// ---------------------------------------------------------------------------
// Scale-0 cost volume: cost[b,h,w,d] = sum_c |fl[b,h,w,c] - fr[b,h,w-d,c]|,
// fr treated as 0 where w < d. Output layout (B,H,W,D), d fastest.
// ---------------------------------------------------------------------------
template <int C>
__global__ void cost0_kernel(const float* __restrict__ fl, const float* __restrict__ fr,
                             float* __restrict__ out, int B, int H, int W, int D) {
    int idx = blockIdx.x * blockDim.x + threadIdx.x;
    int total = B * H * W * D;
    if (idx >= total) return;
    int d = idx % D; int t = idx / D;
    int w = t % W;   t /= W;
    int h = t % H;   int b = t / H;
    const float* pl = fl + (size_t)((b * H + h) * W + w) * C;
    float s = 0.f;
    if (w >= d) {
        const float* pr = fr + (size_t)((b * H + h) * W + (w - d)) * C;
#pragma unroll
        for (int c = 0; c < C; ++c) s += fabsf(pl[c] - pr[c]);
    } else {
#pragma unroll
        for (int c = 0; c < C; ++c) s += fabsf(pl[c]);
    }
    out[idx] = s;
}

// ---------------------------------------------------------------------------
// _build_volume_2d3 with faithful TF tile+reshape scrambling.
// ---------------------------------------------------------------------------
template <int C, int K, int W>
__global__ void cost2d3_kernel(const float* __restrict__ fl, const float* __restrict__ fr,
                               const float* __restrict__ wflow, float* __restrict__ out,
                               int B, int H, int md) {
    int idx = blockIdx.x * blockDim.x + threadIdx.x;
    int total = B * K * H * W;
    if (idx >= total) return;
    int x = idx % W; int t0 = idx / W;
    int y = t0 % H;  int n = t0 / H;
    int a = n / K, t = n % K;

    // flow value (scrambled indexing into wflow)
    int rem2 = (t * H + y) * W + x;
    int hd = rem2 / (W * K);
    int wd = (rem2 / K) % W;
    float bd = wflow[(a * H + hd) * W + wd] - (float)(t - md + 1);

    float xq = (float)x - bd;
    xq = fminf(fmaxf(xq, 0.f), (float)(W - 1));
    int x0 = (int)floorf(xq);
    if (x0 > W - 2) x0 = W - 2;
    float al = xq - (float)x0;

    int base  = ((t * H + y) * W + x)  * C;
    int base0 = ((t * H + y) * W + x0) * C;
    int base1 = base0 + C;

    float s = 0.f;
#pragma unroll
    for (int c = 0; c < C; ++c) {
        int r = base + c;
        int h1 = r / (W * C * K); int w1 = (r / (C * K)) % W; int c1 = (r / K) % C;
        float av = fl[((a * H + h1) * W + w1) * C + c1];

        int r0 = base0 + c;
        int h0 = r0 / (W * C * K); int w0 = (r0 / (C * K)) % W; int c0 = (r0 / K) % C;
        float f0 = fr[((a * H + h0) * W + w0) * C + c0];

        int r1 = base1 + c;
        int h1b = r1 / (W * C * K); int w1b = (r1 / (C * K)) % W; int c1b = (r1 / K) % C;
        float f1 = fr[((a * H + h1b) * W + w1b) * C + c1b];

        float wv = f0 * (1.f - al) + f1 * al;
        s += fabsf(av - wv);
    }
    out[idx] = s;
}

// ---------------------------------------------------------------------------
// 3x3x3 SAME conv, channels-last, strip along d3, thread-level q.
// EXACT r6 body (best measured: scalar seg loads, unroll2 ci, unroll1 kd/kh,
// launch_bounds(256,4) -> 64 VGPR, spill-free). Round-9 change is CONFIG
// ONLY: TD halved at s0 (12->6) and NQ raised at s1 so every conv launches
// >=2048 blocks. r6's 174us was grid-capped at 4 blocks/CU (38% occ); with
// 2048 blocks the LDS (27.6KB -> 5 blocks/CU) allows 20 waves/CU (62%).
// r8 lesson: launch_bounds(256,8) makes the allocator remat-reload from
// global (VGPR=32, 6.6GB FETCH) -- never force 8 waves/EU on this body.
// ---------------------------------------------------------------------------
template <int CIN, int COUT, int CO_BLK, int TD, bool RELU>
__global__ void __launch_bounds__(TPB, 4)
conv3d_strip(const float* __restrict__ in, const float* __restrict__ w,
             float* __restrict__ out, int B, int D1, int D2, int D3) {
    constexpr int NQ  = COUT / CO_BLK;
    constexpr int WSZ = 27 * CIN * COUT;
    __shared__ __align__(16) float ws[WSZ];
    for (int i = threadIdx.x; i < WSZ; i += blockDim.x) ws[i] = w[i];
    __syncthreads();

    const int nblk = D3 / TD;   // exact by construction
    int idx = blockIdx.x * blockDim.x + threadIdx.x;
    int total = B * D1 * D2 * nblk * NQ;
    if (idx >= total) return;
    int q  = idx % NQ;           int t = idx / NQ;
    int t3 = (t % nblk) * TD;    t /= nblk;
    int d2 = t % D2;             t /= D2;
    int d1 = t % D1;             int b = t / D1;

    float acc[TD][CO_BLK];
#pragma unroll
    for (int o = 0; o < TD; ++o)
#pragma unroll
        for (int cb = 0; cb < CO_BLK; ++cb) acc[o][cb] = 0.f;

#pragma unroll 1
    for (int kd = 0; kd < 3; ++kd) {
        int z = d1 + kd - 1; if (z < 0 || z >= D1) continue;
#pragma unroll 1
        for (int kh = 0; kh < 3; ++kh) {
            int y = d2 + kh - 1; if (y < 0 || y >= D2) continue;
            const float* rowp = in + (size_t)((b * D1 + z) * D2 + y) * D3 * CIN;
            const float* wb = ws + (kd * 3 + kh) * 3 * CIN * COUT + q * CO_BLK;

#pragma unroll 2
            for (int ci = 0; ci < CIN; ++ci) {
                float seg[TD + 2];
#pragma unroll
                for (int p = 0; p < TD + 2; ++p) {
                    int x = t3 + p - 1;
                    seg[p] = (x >= 0 && x < D3) ? rowp[x * CIN + ci] : 0.f;
                }
#pragma unroll
                for (int kw = 0; kw < 3; ++kw) {
                    float wq[CO_BLK];
                    if constexpr (CO_BLK == 4) {
                        float4 wv = *(const float4*)(wb + (kw * CIN + ci) * COUT);
                        wq[0] = wv.x; wq[1] = wv.y; wq[2] = wv.z; wq[3] = wv.w;
                    } else if constexpr (CO_BLK == 2) {
                        float2 wv = *(const float2*)(wb + (kw * CIN + ci) * COUT);
                        wq[0] = wv.x; wq[1] = wv.y;
                    } else {
                        wq[0] = wb[(kw * CIN + ci) * COUT];
                    }
#pragma unroll
                    for (int o = 0; o < TD; ++o) {
                        float v = seg[o + kw];
#pragma unroll
                        for (int cb = 0; cb < CO_BLK; ++cb) acc[o][cb] += v * wq[cb];
                    }
                }
            }
        }
    }

    float* op = out + ((size_t)((b * D1 + d1) * D2 + d2) * D3 + t3) * COUT + q * CO_BLK;
#pragma unroll
    for (int o = 0; o < TD; ++o) {
        if constexpr (CO_BLK == 4) {
            float4 v;
            v.x = RELU ? fmaxf(acc[o][0], 0.f) : acc[o][0];
            v.y = RELU ? fmaxf(acc[o][1], 0.f) : acc[o][1];
            v.z = RELU ? fmaxf(acc[o][2], 0.f) : acc[o][2];
            v.w = RELU ? fmaxf(acc[o][3], 0.f) : acc[o][3];
            *(float4*)(op + o * COUT) = v;
        } else if constexpr (CO_BLK == 2) {
            float2 v;
            v.x = RELU ? fmaxf(acc[o][0], 0.f) : acc[o][0];
            v.y = RELU ? fmaxf(acc[o][1], 0.f) : acc[o][1];
            *(float2*)(op + o * COUT) = v;
        } else {
            op[o * COUT] = RELU ? fmaxf(acc[o][0], 0.f) : acc[o][0];
        }
    }
}

// ---------------------------------------------------------------------------
// COUT=1 conv (regularizer output layer). One thread PER VOXEL (d3-fastest
// -> full grid). float4 dot over ci, weights in LDS. r5-r7: not in top-5.
// ---------------------------------------------------------------------------
template <int CIN>
__global__ void __launch_bounds__(TPB)
conv3d_out1(const float* __restrict__ in, const float* __restrict__ w,
            float* __restrict__ out, int B, int D1, int D2, int D3) {
    constexpr int WSZ = 27 * CIN;
    __shared__ __align__(16) float ws[WSZ];
    for (int i = threadIdx.x; i < WSZ; i += blockDim.x) ws[i] = w[i];
    __syncthreads();

    int idx = blockIdx.x * blockDim.x + threadIdx.x;
    int total = B * D1 * D2 * D3;
    if (idx >= total) return;
    int d3 = idx % D3; int t = idx / D3;
    int d2 = t % D2;   t /= D2;
    int d1 = t % D1;   int b = t / D1;

    float acc = 0.f;
#pragma unroll 1
    for (int kd = 0; kd < 3; ++kd) {
        int z = d1 + kd - 1; if (z < 0 || z >= D1) continue;
#pragma unroll 1
        for (int kh = 0; kh < 3; ++kh) {
            int y = d2 + kh - 1; if (y < 0 || y >= D2) continue;
            const float* rowp = in + (size_t)((b * D1 + z) * D2 + y) * D3 * CIN;
            const float* wb = ws + (kd * 3 + kh) * 3 * CIN;
#pragma unroll
            for (int kw = 0; kw < 3; ++kw) {
                int x = d3 + kw - 1; if (x < 0 || x >= D3) continue;
                const float* ip = rowp + x * CIN;
                const float* wp = wb + kw * CIN;
#pragma unroll
                for (int c4 = 0; c4 < CIN / 4; ++c4) {
                    float4 iv = *(const float4*)(ip + c4 * 4);
                    float4 wv = *(const float4*)(wp + c4 * 4);
                    acc += iv.x * wv.x + iv.y * wv.y + iv.z * wv.z + iv.w * wv.w;
                }
            }
        }
    }
    out[idx] = acc;
}

// ---------------------------------------------------------------------------
// softmax(-cost) over last dim D, weighted by dvals = dstart + d
// ---------------------------------------------------------------------------
__global__ void softargmax_kernel(const float* __restrict__ in, float* __restrict__ out,
                                  int npix, int D, float dstart) {
    int idx = blockIdx.x * blockDim.x + threadIdx.x;
    if (idx >= npix) return;
    const float* p = in + (size_t)idx * D;
    float m = -1e30f;
    for (int d = 0; d < D; ++d) m = fmaxf(m, -p[d]);
    float s = 0.f, wsum = 0.f;
    for (int d = 0; d < D; ++d) {
        float e = expf(-p[d] - m);
        s += e;
        wsum += e * (dstart + (float)d);
    }
    out[idx] = wsum / s;
}

// ---------------------------------------------------------------------------
// Bilinear upsample (jax.image.resize upscale == half-pixel + clamp).
// Optional add of prev prediction.
// ---------------------------------------------------------------------------
__global__ void upsample_kernel(const float* __restrict__ disp, int inH, int inW,
                                const float* __restrict__ prev, float* __restrict__ out,
                                int B, int OH, int OW) {
    int idx = blockIdx.x * blockDim.x + threadIdx.x;
    int total = B * OH * OW;
    if (idx >= total) return;
    int x = idx % OW; int t = idx / OW;
    int y = t % OH;   int b = t / OH;
    float sy = (y + 0.5f) * ((float)inH / (float)OH) - 0.5f;
    float sx = (x + 0.5f) * ((float)inW / (float)OW) - 0.5f;
    sy = fminf(fmaxf(sy, 0.f), (float)(inH - 1));
    sx = fminf(fmaxf(sx, 0.f), (float)(inW - 1));
    int y0 = (int)sy; if (y0 > inH - 2) y0 = inH - 2;
    int x0 = (int)sx; if (x0 > inW - 2) x0 = inW - 2;
    float ay = sy - (float)y0, ax = sx - (float)x0;
    const float* p = disp + (size_t)(b * inH + y0) * inW + x0;
    float v00 = p[0], v01 = p[1], v10 = p[inW], v11 = p[inW + 1];
    float v0 = v00 * (1.f - ax) + v01 * ax;
    float v1 = v10 * (1.f - ax) + v11 * ax;
    float v  = v0 * (1.f - ay) + v1 * ay;
    if (prev) v += prev[idx];
    out[idx] = v;
}

// ---------------------------------------------------------------------------
// Antialiased bilinear downsample by integer factor F (jax resize default
// antialias=True): triangle kernel radius F, weights renormalized over valid
// taps. Result multiplied by `mult`.
// ---------------------------------------------------------------------------
__global__ void downsample_kernel(const float* __restrict__ in, int inH, int inW,
                                  float* __restrict__ out, int B, int OH, int OW,
                                  int F, float mult) {
    int idx = blockIdx.x * blockDim.x + threadIdx.x;
    int total = B * OH * OW;
    if (idx >= total) return;
    int x = idx % OW; int t = idx / OW;
    int y = t % OH;   int b = t / OH;
    float sy = (y + 0.5f) * (float)F - 0.5f;
    float sx = (x + 0.5f) * (float)F - 0.5f;
    float invF = 1.f / (float)F;
    int jlo = (int)floorf(sy) - F + 1, jhi = (int)floorf(sy) + F;
    int ilo = (int)floorf(sx) - F + 1, ihi = (int)floorf(sx) + F;

    float wxsum = 0.f;
    for (int i = ilo; i <= ihi; ++i) {
        if (i < 0 || i >= inW) continue;
        float wx = 1.f - fabsf(sx - (float)i) * invF;
        if (wx > 0.f) wxsum += wx;
    }
    float wysum = 0.f, acc = 0.f;
    for (int j = jlo; j <= jhi; ++j) {
        if (j < 0 || j >= inH) continue;
        float wy = 1.f - fabsf(sy - (float)j) * invF;
        if (wy <= 0.f) continue;
        wysum += wy;
        const float* row = in + (size_t)(b * inH + j) * inW;
        float r = 0.f;
        for (int i = ilo; i <= ihi; ++i) {
            if (i < 0 || i >= inW) continue;
            float wx = 1.f - fabsf(sx - (float)i) * invF;
            if (wx > 0.f) r += wx * row[i];
        }
        acc += wy * r;
    }
    out[idx] = mult * acc / (wysum * wxsum);
}

// ---------------------------------------------------------------------------

extern "C" void kernel_launch(void* const* d_in, const int* in_sizes, int n_in,
                              void* d_out, int out_size, void* d_ws, size_t ws_size,
                              hipStream_t stream) {
    const float* fl0 = (const float*)d_in[0];
    const float* fr0 = (const float*)d_in[1];
    const float* fl1 = (const float*)d_in[2];
    const float* fr1 = (const float*)d_in[3];
    const float* fl2 = (const float*)d_in[4];
    const float* fr2 = (const float*)d_in[5];
    const float* w0_in  = (const float*)d_in[6];
    const float* w0_mid = (const float*)d_in[7];
    const float* w0_out = (const float*)d_in[8];
    const float* w1_in  = (const float*)d_in[9];
    const float* w1_mid = (const float*)d_in[10];
    const float* w1_out = (const float*)d_in[11];
    const float* w2_in  = (const float*)d_in[12];
    const float* w2_mid = (const float*)d_in[13];
    const float* w2_out = (const float*)d_in[14];
    float* out = (float*)d_out;

    const int B = 16;
    const int OH = 512, OW = 1024;
    const int P = B * OH * OW;            // one prediction block (fp32 elements)

    const size_t BUF = 10485760;          // max conv volume: 16*128*256*5*4
    float* bufA  = (float*)d_ws;
    float* bufB  = bufA + BUF;
    float* disp  = bufB + BUF;
    float* wflow = disp + 524288;

    // ======================= scale 0 =======================
    {
        const int H = 32, W = 64, D = 12;
        int vox = B * H * W * D;              // 393216
        int npix = B * H * W;                 // 32768
        // TD=6 -> nblk=2; threads = npix*2*NQ(8) = 524288 -> 2048 blocks
        int thr_mid = npix * 2 * 8;
        cost0_kernel<16><<<cdiv(vox, TPB), TPB, 0, stream>>>(fl0, fr0, bufA, B, H, W, D);
        conv3d_strip<1, 16, 2, 6, true ><<<cdiv(thr_mid, TPB), TPB, 0, stream>>>(bufA, w0_in,          bufB, B, H, W, D);
        conv3d_strip<16, 16, 2, 6, true><<<cdiv(thr_mid, TPB), TPB, 0, stream>>>(bufB, w0_mid,         bufA, B, H, W, D);
        conv3d_strip<16, 16, 2, 6, true><<<cdiv(thr_mid, TPB), TPB, 0, stream>>>(bufA, w0_mid + 6912,  bufB, B, H, W, D);
        conv3d_strip<16, 16, 2, 6, true><<<cdiv(thr_mid, TPB), TPB, 0, stream>>>(bufB, w0_mid + 13824, bufA, B, H, W, D);
        conv3d_out1<16><<<cdiv(vox, TPB), TPB, 0, stream>>>(bufA, w0_out, bufB, B, H, W, D);
        softargmax_kernel<<<cdiv(npix, TPB), TPB, 0, stream>>>(bufB, disp, npix, D, 0.f);
        upsample_kernel<<<cdiv(P, TPB), TPB, 0, stream>>>(disp, H, W, nullptr, out, B, OH, OW);
    }

    // ======================= scale 1 =======================
    {
        const int H = 64, W = 128, K = 5, md = 3;
        int npix = B * H * W;                 // 131072
        downsample_kernel<<<cdiv(npix, TPB), TPB, 0, stream>>>(out, OH, OW, wflow, B, H, W, 8, 64.f / 512.f);
        int vox = B * K * H * W;              // 655360
        // CO_BLK=1, NQ=4 -> threads = npix*4 = 524288 -> 2048 blocks
        int thr4 = npix * 4;
        cost2d3_kernel<16, 5, 128><<<cdiv(vox, TPB), TPB, 0, stream>>>(fl1, fr1, wflow, bufA, B, H, md);
        conv3d_strip<1, 4, 1, 5, true ><<<cdiv(thr4, TPB), TPB, 0, stream>>>(bufA, w1_in,        bufB, B, H, W, K);
        conv3d_strip<4, 4, 1, 5, true ><<<cdiv(thr4, TPB), TPB, 0, stream>>>(bufB, w1_mid,       bufA, B, H, W, K);
        conv3d_strip<4, 4, 1, 5, true ><<<cdiv(thr4, TPB), TPB, 0, stream>>>(bufA, w1_mid + 432, bufB, B, H, W, K);
        conv3d_strip<4, 4, 1, 5, true ><<<cdiv(thr4, TPB), TPB, 0, stream>>>(bufB, w1_mid + 864, bufA, B, H, W, K);
        conv3d_out1<4><<<cdiv(vox, TPB), TPB, 0, stream>>>(bufA, w1_out, bufB, B, H, W, K);
        softargmax_kernel<<<cdiv(npix, TPB), TPB, 0, stream>>>(bufB, disp, npix, K, -2.f);
        upsample_kernel<<<cdiv(P, TPB), TPB, 0, stream>>>(disp, H, W, out, out + P, B, OH, OW);
    }

    // ======================= scale 2 =======================
    {
        const int H = 128, W = 256, K = 5, md = 3;
        int npix = B * H * W;                 // 524288
        downsample_kernel<<<cdiv(npix, TPB), TPB, 0, stream>>>(out + P, OH, OW, wflow, B, H, W, 4, 128.f / 512.f);
        int vox = B * K * H * W;              // 2621440
        // CO_BLK=2, NQ=2 -> threads = npix*2 = 1048576 -> 4096 blocks (as r6)
        int thr2 = npix * 2;
        cost2d3_kernel<16, 5, 256><<<cdiv(vox, TPB), TPB, 0, stream>>>(fl2, fr2, wflow, bufA, B, H, md);
        conv3d_strip<1, 4, 2, 5, true ><<<cdiv(thr2, TPB), TPB, 0, stream>>>(bufA, w2_in,        bufB, B, H, W, K);
        conv3d_strip<4, 4, 2, 5, true ><<<cdiv(thr2, TPB), TPB, 0, stream>>>(bufB, w2_mid,       bufA, B, H, W, K);
        conv3d_strip<4, 4, 2, 5, true ><<<cdiv(thr2, TPB), TPB, 0, stream>>>(bufA, w2_mid + 432, bufB, B, H, W, K);
        conv3d_strip<4, 4, 2, 5, true ><<<cdiv(thr2, TPB), TPB, 0, stream>>>(bufB, w2_mid + 864, bufA, B, H, W, K);
        conv3d_out1<4><<<cdiv(vox, TPB), TPB, 0, stream>>>(bufA, w2_out, bufB, B, H, W, K);
        softargmax_kernel<<<cdiv(npix, TPB), TPB, 0, stream>>>(bufB, disp, npix, K, -2.f);
        upsample_kernel<<<cdiv(P, TPB), TPB, 0, stream>>>(disp, H, W, out + P, out + 2 * P, B, OH, OW);
    }
}